// Round 1
// baseline (165.359 us; speedup 1.0000x reference)
//
#include <hip/hip_runtime.h>

// Problem constants (fixed by the reference setup)
#define B_ 64
#define T_ 32
#define H_ 256
#define NMAX_ 64
#define GRID 2048     // 2048 blocks x 2 tiles = 4096 tiles (64 rows x 128 cols each)
#define BLOCK 256
#define HSROW 136     // Hs row stride in shorts (128 + 8 pad)

typedef __attribute__((ext_vector_type(8))) short short8;  // 8 bf16 = 4 VGPRs
typedef __attribute__((ext_vector_type(4))) float f32x4;   // MFMA C/D frag

// float -> bf16 bits, round-to-nearest-even (values are finite here)
__device__ __forceinline__ short f2bf(float f) {
    unsigned u = __builtin_bit_cast(unsigned, f);
    u = (u + 0x7fffu + ((u >> 16) & 1u)) >> 16;
    return (short)u;
}

// Workgroup barrier WITHOUT the vmcnt(0) store drain __syncthreads would emit.
// LDS visibility needs only lgkmcnt(0); global stores are fire-and-forget.
__device__ __forceinline__ void barrier_nodrain() {
    asm volatile("s_waitcnt lgkmcnt(0)\n\ts_barrier" ::: "memory");
}

// Occupancy target: 4 blocks/CU (16 waves/CU). LDS ~20.4 KB/block, VGPR aimed <=128.
__global__ __launch_bounds__(BLOCK, 4)
void pe_fused(const float* __restrict__ bbox,
              const float* __restrict__ W1,
              const float* __restrict__ b1,
              const float* __restrict__ W2,
              const float* __restrict__ b2,
              const int*   __restrict__ npf,
              float* __restrict__ out,
              int NT)   // total bbox rows = N*T
{
    __shared__ float4 W1t[128];       // transposed W1: (W1[0][h],W1[1][h],W1[2][h],W1[3][h])
    __shared__ float  b1s[128];
    __shared__ int    s_n[64];        // npf[b]
    __shared__ int    s_start[64];    // exclusive cumsum of npf
    __shared__ short  Hs[64 * HSROW]; // 64 rows x 128 bf16 hidden (single buffer)

    const int tid  = threadIdx.x;
    const int wave = tid >> 6;
    const int lane = tid & 63;
    const int q    = lane >> 4;   // quad within wave
    const int m16  = lane & 15;

    // Tile decomposition: tile = (b, l0-pair) x column-half. Block does the SAME
    // column half for two pairs: p0 (b in [0,32)) and p0+1024 (b in [32,64)).
    const int ch = blockIdx.x & 1;        // column half: cols [ch*128, ch*128+128)
    const int p0 = blockIdx.x >> 1;       // first (b,l0)-pair id

    // ---- Block setup (once) ----
    if (tid < 128) {
        W1t[tid] = make_float4(W1[tid], W1[128 + tid], W1[256 + tid], W1[384 + tid]);
        b1s[tid] = b1[tid];
    }
    // Exclusive prefix sum of npf via wave-0 shuffle scan.
    if (wave == 0) {
        int v = npf[lane];
        s_n[lane] = v;
        int s = v;
#pragma unroll
        for (int d = 1; d < 64; d <<= 1) {
            int u = __shfl_up(s, d, 64);
            if (lane >= d) s += u;
        }
        s_start[lane] = s - v;
    }

    // W2^T fragments (A operand) for this wave's 32 output columns, bf16.
    // A[m=col(m16)][k=kc*32+q*8+jj]; D then gives each lane 4 consecutive h.
    const int colw = ch * 128 + wave * 32;
    short8 Wf[2][4];
#pragma unroll
    for (int ct = 0; ct < 2; ++ct)
#pragma unroll
        for (int kc = 0; kc < 4; ++kc) {
            short8 f;
#pragma unroll
            for (int jj = 0; jj < 8; ++jj)
                f[jj] = f2bf(W2[(kc * 32 + q * 8 + jj) * H_ + colw + ct * 16 + m16]);
            Wf[ct][kc] = f;
        }
    float4 b2v[2];   // bias folded into acc init
#pragma unroll
    for (int ct = 0; ct < 2; ++ct)
        b2v[ct] = *(const float4*)(b2 + colw + ct * 16 + q * 4);

    barrier_nodrain();   // W1t/b1s/s_n/s_start visible

#pragma unroll
    for (int it = 0; it < 2; ++it) {
        const int pair = it ? (p0 + 1024) : p0;
        const int b    = pair >> 5;
        const int l0   = (pair & 31) * 2;
        const int nb   = s_n[b];

        const int ob0 = (l0 * (B_ * T_) + b * T_) * H_;  // out float idx of (l0,  b, t=0)
        const int ob1 = ob0 + (B_ * T_) * H_;            // out float idx of (l0+1,b, t=0)

        if (l0 >= nb) {
            // Whole tile invalid (block-uniform): zero-fill 64 rows x 512B half-rows.
            // One store instr = 2 rows x 512B contiguous. No barriers on this path.
            const float4 z = make_float4(0.f, 0.f, 0.f, 0.f);
            const int col = ch * 128 + (lane & 31) * 4;
#pragma unroll
            for (int j = 0; j < 8; ++j) {
                const int r = wave * 16 + j * 2 + (lane >> 5);   // row 0..63
                float* dst = out + (r < 32 ? ob0 + r * H_ : ob1 + (r - 32) * H_) + col;
                *(float4*)dst = z;
            }
            continue;
        }

        barrier_nodrain();   // prior tile's Hs readers done before overwrite

        // ---- Layer 1: hidden = relu(bbox @ W1 + b1), fp32 -> bf16 into LDS ----
        {
            const int r4 = tid >> 2;   // row 0..63
            const int c4 = tid & 3;    // 32-h chunk
            const int g  = (s_start[b] + l0) * T_ + r4;
            float4 bv = make_float4(0.f, 0.f, 0.f, 0.f);
            if (g < NT) bv = *(const float4*)(bbox + g * 4);
            short* hrow = &Hs[r4 * HSROW + c4 * 32];
#pragma unroll
            for (int w = 0; w < 4; ++w) {
                short8 hv;
#pragma unroll
                for (int jj = 0; jj < 8; ++jj) {
                    const int h = c4 * 32 + w * 8 + jj;
                    const float4 wv = W1t[h];     // one ds_read_b128 per h
                    float v = b1s[h];
                    v = fmaf(bv.x, wv.x, v);
                    v = fmaf(bv.y, wv.y, v);
                    v = fmaf(bv.z, wv.z, v);
                    v = fmaf(bv.w, wv.w, v);
                    v = fmaxf(v, 0.f);
                    hv[jj] = f2bf(v);
                }
                *(short8*)(hrow + w * 8) = hv;
            }
        }
        barrier_nodrain();

        // ---- Layer 2 (transposed orientation): D[m=h][n=row] = W2^T x H^T ----
        f32x4 acc[2][4];   // [ct][rt], bias-initialized
#pragma unroll
        for (int ct = 0; ct < 2; ++ct)
#pragma unroll
            for (int rt = 0; rt < 4; ++rt)
                acc[ct][rt] = (f32x4){b2v[ct].x, b2v[ct].y, b2v[ct].z, b2v[ct].w};

#pragma unroll
        for (int kc = 0; kc < 4; ++kc) {
            short8 hf[4];
#pragma unroll
            for (int rt = 0; rt < 4; ++rt)  // B-operand: H[n=rt*16+m16][k0..k0+7]
                hf[rt] = *(const short8*)&Hs[(rt * 16 + m16) * HSROW + kc * 32 + q * 8];
#pragma unroll
            for (int ct = 0; ct < 2; ++ct)
#pragma unroll
                for (int rt = 0; rt < 4; ++rt)
                    acc[ct][rt] = __builtin_amdgcn_mfma_f32_16x16x32_bf16(
                        Wf[ct][kc], hf[rt], acc[ct][rt], 0, 0, 0);
        }

        // ---- Epilogue: direct stores from acc. acc[ct][rt] holds out row
        // rt*16+m16 (rows 0..31 -> slot l0, 32..63 -> slot l0+1),
        // h = colw + ct*16 + q*4 + [0,4): 16B/lane, 64B-aligned 64B segments.
        const bool v1 = (l0 + 1) < nb;
#pragma unroll
        for (int ct = 0; ct < 2; ++ct) {
            const int cb = colw + ct * 16 + q * 4;
#pragma unroll
            for (int rt = 0; rt < 4; ++rt) {
                const int t = (rt & 1) * 16 + m16;
                float* dst = out + (rt < 2 ? ob0 : ob1) + t * H_ + cb;
                float4 val;
                if (rt >= 2 && !v1) {
                    val = make_float4(0.f, 0.f, 0.f, 0.f);  // invalid slot l0+1
                } else {
                    const f32x4 a = acc[ct][rt];
                    val = make_float4(a[0], a[1], a[2], a[3]);
                }
                *(float4*)dst = val;
            }
        }
    }
}

extern "C" void kernel_launch(void* const* d_in, const int* in_sizes, int n_in,
                              void* d_out, int out_size, void* d_ws, size_t ws_size,
                              hipStream_t stream)
{
    const float* bbox = (const float*)d_in[0];
    const float* W1   = (const float*)d_in[1];
    const float* b1   = (const float*)d_in[2];
    const float* W2   = (const float*)d_in[3];
    const float* b2   = (const float*)d_in[4];
    const int*   npf  = (const int*)d_in[5];
    const int NT = in_sizes[0] / 4;  // N*T

    pe_fused<<<GRID, BLOCK, 0, stream>>>(bbox, W1, b1, W2, b2, npf,
                                         (float*)d_out, NT);
}

// Round 3
// 161.780 us; speedup vs baseline: 1.0221x; 1.0221x over previous
//
#include <hip/hip_runtime.h>

// Problem constants (fixed by the reference setup)
#define B_ 64
#define T_ 32
#define H_ 256
#define NMAX_ 64
#define GRID 1024    // 1024 blocks x 2 tiles = 2048 tiles (64 rows x 256 cols)
#define BLOCK 256
#define HSROW 136    // Hs row stride in shorts (272B rows; measured 0 bank conflicts)
#define SROW 260     // stage row stride in dwords (1040B rows, 16B-aligned)

typedef __attribute__((ext_vector_type(8))) short short8;  // 8 bf16 = 4 VGPRs
typedef __attribute__((ext_vector_type(4))) float f32x4;   // MFMA C/D frag

// float -> bf16 bits, round-to-nearest-even (values are finite here)
__device__ __forceinline__ short f2bf(float f) {
    unsigned u = __builtin_bit_cast(unsigned, f);
    u = (u + 0x7fffu + ((u >> 16) & 1u)) >> 16;
    return (short)u;
}

// Workgroup barrier WITHOUT the vmcnt(0) store drain __syncthreads would emit.
// LDS visibility needs only lgkmcnt(0); global stores are fire-and-forget.
__device__ __forceinline__ void barrier_nodrain() {
    asm volatile("s_waitcnt lgkmcnt(0)\n\ts_barrier" ::: "memory");
}

// 3 blocks/CU: LDS 37376B (3x fits 160KB easily), VGPR cap 170 (est ~158).
__global__ __launch_bounds__(BLOCK, 3)
void pe_fused(const float* __restrict__ bbox,
              const float* __restrict__ W1,
              const float* __restrict__ b1,
              const float* __restrict__ W2,
              const float* __restrict__ b2,
              const int*   __restrict__ npf,
              float* __restrict__ out,
              int NT)   // total bbox rows = N*T
{
    __shared__ float4 W1t[128];        // transposed W1: (W1[0][h],W1[1][h],W1[2][h],W1[3][h])
    __shared__ float  b1s[128];
    __shared__ float  b2s[256];
    __shared__ int    s_n[64];
    __shared__ int    s_start[64];
    // UNION: Hs (bf16 hidden, 17408B) and stage (f32 rows, 33280B) are live in
    // disjoint phases of a tile; barriers B2/B4/B6 below order the handoffs.
    __shared__ float  smem[32 * SROW]; // 33280 B

    short* const Hs    = (short*)smem;
    float* const stage = smem;

    const int tid  = threadIdx.x;
    const int wave = tid >> 6;
    const int lane = tid & 63;
    const int q    = lane >> 4;   // quad within wave
    const int m16  = lane & 15;

    // ---- Block setup (once) ----
    if (tid < 128) {
        W1t[tid] = make_float4(W1[tid], W1[128 + tid], W1[256 + tid], W1[384 + tid]);
        b1s[tid] = b1[tid];
    }
    b2s[tid] = b2[tid];
    // Exclusive prefix sum of npf via wave-0 shuffle scan.
    if (wave == 0) {
        int v = npf[lane];
        s_n[lane] = v;
        int s = v;
#pragma unroll
        for (int d = 1; d < 64; d <<= 1) {
            int u = __shfl_up(s, d, 64);
            if (lane >= d) s += u;
        }
        s_start[lane] = s - v;
    }

    // W2^T fragments (A operand) in registers, bf16. Wave w owns cols [64w, 64w+64).
    short8 Wf[4][4];
#pragma unroll
    for (int ct = 0; ct < 4; ++ct)
#pragma unroll
        for (int kc = 0; kc < 4; ++kc) {
            const int k0 = kc * 32 + q * 8;
            short8 f;
#pragma unroll
            for (int jj = 0; jj < 8; ++jj)
                f[jj] = f2bf(W2[(k0 + jj) * H_ + wave * 64 + ct * 16 + m16]);
            Wf[ct][kc] = f;
        }
    __syncthreads();   // W1t/b1s/b2s/s_n/s_start ready

    const int r4 = tid >> 2;  // layer-1 row 0..63
    const int c4 = tid & 3;   // layer-1 h-chunk (32 hidden each)

    // ---- Preload both tiles' bbox rows (no global loads inside the loop).
    float4 bb[2];
#pragma unroll
    for (int i = 0; i < 2; ++i) {
        const int tt = blockIdx.x + i * GRID;
        const int b  = tt >> 5;
        const int l0 = (tt & 31) * 2;
        const int g  = (s_start[b] + l0) * T_ + r4;
        bb[i] = make_float4(0.f, 0.f, 0.f, 0.f);
        if (g < NT) bb[i] = *(const float4*)(bbox + g * 4);
    }

#pragma unroll
    for (int i = 0; i < 2; ++i) {
        const int tt = blockIdx.x + i * GRID;
        const int b  = tt >> 5;
        const int l0 = (tt & 31) * 2;
        const int nb = s_n[b];

        const int ob0 = (l0 * (B_ * T_) + b * T_) * H_;  // out row (l0,  b, t=0)
        const int ob1 = ob0 + (B_ * T_) * H_;            // out row (l0+1,b, t=0)

        if (l0 >= nb) {
            // Whole tile invalid (block-uniform): zero-fill 64 rows x 1KB,
            // one store instr = one contiguous 1KB row (full-line requests).
            const float4 z = make_float4(0.f, 0.f, 0.f, 0.f);
#pragma unroll
            for (int rr = 0; rr < 16; ++rr) {
                const int r = rr * 4 + wave;   // wave-uniform row
                float* dst = out + (r < 32 ? ob0 + r * H_ : ob1 + (r - 32) * H_);
                *(float4*)(dst + lane * 4) = z;
            }
            continue;   // block-uniform branch; no LDS touched on this path
        }

        // ---- Layer 1: hidden = relu(bbox @ W1 + b1), fp32 -> bf16 into LDS ----
        {
            const float4 bv = bb[i];
            short* hrow = &Hs[r4 * HSROW + c4 * 32];
#pragma unroll
            for (int w = 0; w < 4; ++w) {
                short8 hv;
#pragma unroll
                for (int jj = 0; jj < 8; ++jj) {
                    const int h = c4 * 32 + w * 8 + jj;
                    const float4 wv = W1t[h];     // one ds_read_b128 per h
                    float v = b1s[h];
                    v = fmaf(bv.x, wv.x, v);
                    v = fmaf(bv.y, wv.y, v);
                    v = fmaf(bv.z, wv.z, v);
                    v = fmaf(bv.w, wv.w, v);
                    v = fmaxf(v, 0.f);
                    hv[jj] = f2bf(v);
                }
                *(short8*)(hrow + w * 8) = hv;
            }
        }
        barrier_nodrain();   // B1: Hs ready

        // ---- Layer 2 (transposed orientation): D[m=h][n=row] = W2^T x H^T ----
        // Bias folded into acc init (b2 quad from LDS; saves 16 VGPRs).
        f32x4 acc[4][4];   // [ct][rt]
#pragma unroll
        for (int ct = 0; ct < 4; ++ct) {
            const float4 bq = *(const float4*)&b2s[wave * 64 + ct * 16 + q * 4];
#pragma unroll
            for (int rt = 0; rt < 4; ++rt)
                acc[ct][rt] = (f32x4){bq.x, bq.y, bq.z, bq.w};
        }

#pragma unroll
        for (int kc = 0; kc < 4; ++kc) {
            short8 hf[4];
#pragma unroll
            for (int rt = 0; rt < 4; ++rt)  // B-operand: H[n=rt*16+m16][k0..k0+7]
                hf[rt] = *(const short8*)&Hs[(rt * 16 + m16) * HSROW + kc * 32 + q * 8];
#pragma unroll
            for (int ct = 0; ct < 4; ++ct)
#pragma unroll
                for (int rt = 0; rt < 4; ++rt)
                    acc[ct][rt] = __builtin_amdgcn_mfma_f32_16x16x32_bf16(
                        Wf[ct][kc], hf[rt], acc[ct][rt], 0, 0, 0);
        }
        barrier_nodrain();   // B2: all waves' Hs reads done (union safety)

        // ---- Epilogue: LDS-transpose 32 rows at a time, full-row stores ----
        // acc[ct][rt]: output row rt*16+m16, h = wave*64 + ct*16 + q*4 + [0,4).
        const bool v1 = (l0 + 1) < nb;
#pragma unroll
        for (int half = 0; half < 2; ++half) {
            const int obh = half ? ob1 : ob0;
            if (half == 1 && !v1) {
                // Invalid slot l0+1 (block-uniform): store zeros, skip staging.
                const float4 z = make_float4(0.f, 0.f, 0.f, 0.f);
#pragma unroll
                for (int j = 0; j < 8; ++j)
                    *(float4*)(out + obh + (wave * 8 + j) * H_ + lane * 4) = z;
                continue;
            }
            // Stage rows [32*half, 32*half+32): rt = 2*half + {0,1}
#pragma unroll
            for (int rt2 = 0; rt2 < 2; ++rt2) {
                const int rt = 2 * half + rt2;
                const int u  = rt2 * 16 + m16;       // row within half
#pragma unroll
                for (int ct = 0; ct < 4; ++ct) {
                    const f32x4 d = acc[ct][rt];
                    *(float4*)&stage[u * SROW + wave * 64 + ct * 16 + q * 4] =
                        make_float4(d[0], d[1], d[2], d[3]);
                }
            }
            barrier_nodrain();   // B3/B5: stage ready
            // Store: one instruction = one full 1KB row (64 lanes x 16B).
#pragma unroll
            for (int j = 0; j < 8; ++j) {
                const int u = wave * 8 + j;
                const float4 v = *(const float4*)&stage[u * SROW + lane * 4];
                *(float4*)(out + obh + u * H_ + lane * 4) = v;
            }
            barrier_nodrain();   // B4/B6: stage reads done (reuse / next-tile Hs safety)
        }
    }
}

extern "C" void kernel_launch(void* const* d_in, const int* in_sizes, int n_in,
                              void* d_out, int out_size, void* d_ws, size_t ws_size,
                              hipStream_t stream)
{
    const float* bbox = (const float*)d_in[0];
    const float* W1   = (const float*)d_in[1];
    const float* b1   = (const float*)d_in[2];
    const float* W2   = (const float*)d_in[3];
    const float* b2   = (const float*)d_in[4];
    const int*   npf  = (const int*)d_in[5];
    const int NT = in_sizes[0] / 4;  // N*T

    pe_fused<<<GRID, BLOCK, 0, stream>>>(bbox, W1, b1, W2, b2, npf,
                                         (float*)d_out, NT);
}

// Round 4
// 157.755 us; speedup vs baseline: 1.0482x; 1.0255x over previous
//
#include <hip/hip_runtime.h>

// Problem constants (fixed by the reference setup)
#define B_ 64
#define T_ 32
#define H_ 256
#define NMAX_ 64
#define GRID 512     // 512 blocks x 4 tiles = 2048 tiles (64 rows x 256 cols each)
#define BLOCK 512    // 8 waves/block, each wave owns 32 output columns
#define HSROW 136    // Hs row stride in shorts (272B rows; 0 bank conflicts measured)
#define SROW 260     // stage row stride in dwords (1040B rows, 16B-aligned)

typedef __attribute__((ext_vector_type(8))) short short8;  // 8 bf16 = 4 VGPRs
typedef __attribute__((ext_vector_type(4))) float f32x4;   // MFMA C/D frag

// float -> bf16 bits, round-to-nearest-even (values are finite here)
__device__ __forceinline__ short f2bf(float f) {
    unsigned u = __builtin_bit_cast(unsigned, f);
    u = (u + 0x7fffu + ((u >> 16) & 1u)) >> 16;
    return (short)u;
}

// Workgroup barrier WITHOUT the vmcnt(0) store drain __syncthreads would emit.
// LDS visibility needs only lgkmcnt(0); global stores are fire-and-forget.
__device__ __forceinline__ void barrier_nodrain() {
    asm volatile("s_waitcnt lgkmcnt(0)\n\ts_barrier" ::: "memory");
}

// 4 waves/SIMD (= 2 blocks/CU = 16 waves/CU) -> VGPR cap 128. Est usage ~120.
// LDS 54.8KB/block x 2 = 109.6KB/CU (fits 160KB).
__global__ __launch_bounds__(BLOCK, 4)
void pe_fused(const float* __restrict__ bbox,
              const float* __restrict__ W1,
              const float* __restrict__ b1,
              const float* __restrict__ W2,
              const float* __restrict__ b2,
              const int*   __restrict__ npf,
              float* __restrict__ out,
              int NT)   // total bbox rows = N*T
{
    __shared__ float4 W1t[128];        // transposed W1: (W1[0][h],W1[1][h],W1[2][h],W1[3][h])
    __shared__ float  b1s[128];
    __shared__ float  b2s[256];
    __shared__ int    s_n[64];
    __shared__ int    s_start[64];
    __shared__ short  Hs[64 * HSROW];  // 64 rows x 128 bf16 hidden (single buffer)
    __shared__ float  stage[32 * SROW];// 32 output rows staged for full-line stores

    const int tid  = threadIdx.x;
    const int wave = tid >> 6;    // 0..7
    const int lane = tid & 63;
    const int q    = lane >> 4;   // quad within wave
    const int m16  = lane & 15;

    // ---- Block setup (once) ----
    if (tid < 128) {
        W1t[tid] = make_float4(W1[tid], W1[128 + tid], W1[256 + tid], W1[384 + tid]);
        b1s[tid] = b1[tid];
    }
    if (tid < 256) b2s[tid] = b2[tid];
    // Exclusive prefix sum of npf via wave-0 shuffle scan.
    if (wave == 0) {
        int v = npf[lane];
        s_n[lane] = v;
        int s = v;
#pragma unroll
        for (int d = 1; d < 64; d <<= 1) {
            int u = __shfl_up(s, d, 64);
            if (lane >= d) s += u;
        }
        s_start[lane] = s - v;
    }

    // W2^T fragments (A operand) in registers, bf16. Wave w owns cols [32w, 32w+32).
    const int colw = wave * 32;
    short8 Wf[2][4];
#pragma unroll
    for (int ct = 0; ct < 2; ++ct)
#pragma unroll
        for (int kc = 0; kc < 4; ++kc) {
            const int k0 = kc * 32 + q * 8;
            short8 f;
#pragma unroll
            for (int jj = 0; jj < 8; ++jj)
                f[jj] = f2bf(W2[(k0 + jj) * H_ + colw + ct * 16 + m16]);
            Wf[ct][kc] = f;
        }
    __syncthreads();   // W1t/b1s/b2s/s_n/s_start ready

    const int r8 = tid >> 3;  // layer-1 row 0..63
    const int c8 = tid & 7;   // layer-1 h-chunk (16 hidden each)

    // ---- Preload ALL 4 tiles' bbox rows (no global loads inside the loop).
    float4 bb[4];
#pragma unroll
    for (int i = 0; i < 4; ++i) {
        const int tt = blockIdx.x + i * GRID;
        const int b  = tt >> 5;
        const int l0 = (tt & 31) * 2;
        const int g  = (s_start[b] + l0) * T_ + r8;
        bb[i] = make_float4(0.f, 0.f, 0.f, 0.f);
        if (g < NT) bb[i] = *(const float4*)(bbox + g * 4);
    }

#pragma unroll
    for (int i = 0; i < 4; ++i) {
        const int tt = blockIdx.x + i * GRID;
        const int b  = tt >> 5;
        const int l0 = (tt & 31) * 2;
        const int nb = s_n[b];

        const int ob0 = (l0 * (B_ * T_) + b * T_) * H_;  // out row (l0,  b, t=0)
        const int ob1 = ob0 + (B_ * T_) * H_;            // out row (l0+1,b, t=0)

        if (l0 >= nb) {
            // Whole tile invalid (block-uniform): zero-fill 64 rows x 1KB,
            // one store instr = one contiguous 1KB row (full-line requests).
            const float4 z = make_float4(0.f, 0.f, 0.f, 0.f);
#pragma unroll
            for (int rr = 0; rr < 8; ++rr) {
                const int r = rr * 8 + wave;   // wave-uniform row 0..63
                float* dst = out + (r < 32 ? ob0 + r * H_ : ob1 + (r - 32) * H_);
                *(float4*)(dst + lane * 4) = z;
            }
            continue;   // block-uniform branch; no barrier on this path
        }

        // ---- Layer 1: hidden = relu(bbox @ W1 + b1), fp32 -> bf16 into LDS ----
        {
            const float4 bv = bb[i];
            short* hrow = &Hs[r8 * HSROW + c8 * 16];
#pragma unroll
            for (int w = 0; w < 2; ++w) {
                short8 hv;
#pragma unroll
                for (int jj = 0; jj < 8; ++jj) {
                    const int h = c8 * 16 + w * 8 + jj;
                    const float4 wv = W1t[h];     // one ds_read_b128 per h
                    float v = b1s[h];
                    v = fmaf(bv.x, wv.x, v);
                    v = fmaf(bv.y, wv.y, v);
                    v = fmaf(bv.z, wv.z, v);
                    v = fmaf(bv.w, wv.w, v);
                    v = fmaxf(v, 0.f);
                    hv[jj] = f2bf(v);
                }
                *(short8*)(hrow + w * 8) = hv;
            }
        }
        barrier_nodrain();   // B1: Hs ready

        // ---- Layer 2 (transposed orientation): D[m=h][n=row] = W2^T x H^T ----
        // Bias folded into acc init (b2 quad from LDS).
        f32x4 acc[2][4];   // [ct][rt]
#pragma unroll
        for (int ct = 0; ct < 2; ++ct) {
            const float4 bq = *(const float4*)&b2s[colw + ct * 16 + q * 4];
#pragma unroll
            for (int rt = 0; rt < 4; ++rt)
                acc[ct][rt] = (f32x4){bq.x, bq.y, bq.z, bq.w};
        }

#pragma unroll
        for (int kc = 0; kc < 4; ++kc) {
            short8 hf[4];
#pragma unroll
            for (int rt = 0; rt < 4; ++rt)  // B-operand: H[n=rt*16+m16][k0..k0+7]
                hf[rt] = *(const short8*)&Hs[(rt * 16 + m16) * HSROW + kc * 32 + q * 8];
#pragma unroll
            for (int ct = 0; ct < 2; ++ct)
#pragma unroll
                for (int rt = 0; rt < 4; ++rt)
                    acc[ct][rt] = __builtin_amdgcn_mfma_f32_16x16x32_bf16(
                        Wf[ct][kc], hf[rt], acc[ct][rt], 0, 0, 0);
        }
        // (Hs reads drain at the next lgkm barrier; next-tile L1 writes come
        //  only after B4/B6, so the single Hs buffer is safe — as in R0.)

        // ---- Epilogue: +b2 (folded), LDS-transpose 32 rows, full-row stores ----
        // acc[ct][rt]: output row rt*16+m16, h = colw + ct*16 + q*4 + [0,4).
        const bool v1 = (l0 + 1) < nb;
#pragma unroll
        for (int half = 0; half < 2; ++half) {
            const int obh = half ? ob1 : ob0;
            if (half == 1 && !v1) {
                // Invalid slot l0+1 (block-uniform): store zeros, skip staging.
                const float4 z = make_float4(0.f, 0.f, 0.f, 0.f);
#pragma unroll
                for (int j = 0; j < 4; ++j)
                    *(float4*)(out + obh + (wave * 4 + j) * H_ + lane * 4) = z;
                continue;
            }
            // Stage rows [32*half, 32*half+32): rt = 2*half + {0,1}
#pragma unroll
            for (int rt2 = 0; rt2 < 2; ++rt2) {
                const int rt = 2 * half + rt2;
                const int u  = rt2 * 16 + m16;       // row within half
#pragma unroll
                for (int ct = 0; ct < 2; ++ct) {
                    const f32x4 d = acc[ct][rt];
                    *(float4*)&stage[u * SROW + colw + ct * 16 + q * 4] =
                        make_float4(d[0], d[1], d[2], d[3]);
                }
            }
            barrier_nodrain();   // B2/B4: stage ready
            // Store: one instruction = one full 1KB row (64 lanes x 16B).
#pragma unroll
            for (int j = 0; j < 4; ++j) {
                const int u = wave * 4 + j;
                const float4 v = *(const float4*)&stage[u * SROW + lane * 4];
                *(float4*)(out + obh + u * H_ + lane * 4) = v;
            }
            barrier_nodrain();   // B3/B5: stage reads done (reuse / next-tile Hs safety)
        }
    }
}

extern "C" void kernel_launch(void* const* d_in, const int* in_sizes, int n_in,
                              void* d_out, int out_size, void* d_ws, size_t ws_size,
                              hipStream_t stream)
{
    const float* bbox = (const float*)d_in[0];
    const float* W1   = (const float*)d_in[1];
    const float* b1   = (const float*)d_in[2];
    const float* W2   = (const float*)d_in[3];
    const float* b2   = (const float*)d_in[4];
    const int*   npf  = (const int*)d_in[5];
    const int NT = in_sizes[0] / 4;  // N*T

    pe_fused<<<GRID, BLOCK, 0, stream>>>(bbox, W1, b1, W2, b2, npf,
                                         (float*)d_out, NT);
}